// Round 3
// baseline (906.550 us; speedup 1.0000x reference)
//
#include <hip/hip_runtime.h>
#include <hip/hip_bf16.h>

// out[b,k,o,f] = entmax15( x[b,f,:] @ W2'[k,:,o] ) * values[k,o,f]
// W2'[k,x,o] = 0.0625 * sum_y bw[k,x,y] * q[k,o,y]   (scale * (alpha-1) folded in)
// b=2048, k=8, o=64, f=128, x=128, y=64
//
// Round-3 structure: NO LDS, NO barriers in the hot kernel.
// MFMA computes z^T: A = x[b] ([f][x] rows), B = W2 ([o][x] rows), both read as
// half8 fragments straight from global (L2-resident, XCD-local bid remap).
// C layout: f = mt*16 + q*4 + r, o = w*16 + c16 -> each lane's 32 acc values are
// 32 f's of ONE o-row; entmax reduces via shfl_xor 16/32. Occupancy 3->6 blk/CU.

using half8_t  = __attribute__((ext_vector_type(8))) _Float16;
using half4_t  = __attribute__((ext_vector_type(4))) _Float16;
using fp16x2   = __attribute__((ext_vector_type(2))) __fp16;   // builtin-compatible
using floatx4  = __attribute__((ext_vector_type(4))) float;

#define NBIS 8    // fp16 bisection iters -> bracket width 0.91*2^-8*2 = 7.1e-3

#if defined(__has_builtin)
#if __has_builtin(__builtin_amdgcn_fdot2)
#define HAS_FDOT2 1
#endif
#endif
#ifndef HAS_FDOT2
#define HAS_FDOT2 0
#endif

__device__ __forceinline__ float frcp(float x) {
#if __has_builtin(__builtin_amdgcn_rcpf)
    return __builtin_amdgcn_rcpf(x);   // 1-ulp rcp; plenty for Newton step sizing
#else
    return 1.0f / x;
#endif
}

// ---------------- Kernel A: W2'[k][o][x] fp16 into workspace ----------------
__global__ __launch_bounds__(256) void w2_kernel(const float* __restrict__ bw,
                                                 const float* __restrict__ qm,
                                                 _Float16* __restrict__ W2h) {
    const int k  = blockIdx.x >> 3;
    const int og = blockIdx.x & 7;          // o-chunk of 8 rows
    __shared__ float Lbw[128 * 65];         // [x][y] padded (+1) -> conflict-free
    __shared__ float Lq[8 * 64];            // [o][y]
    const int t = threadIdx.x;

    const float* bwk = bw + k * 8192;       // [128][64]
    #pragma unroll
    for (int i2 = 0; i2 < 8; ++i2) {
        int i = t + i2 * 256;               // float4 index, 2048 total
        float4 v = ((const float4*)bwk)[i];
        int xx = (i * 4) >> 6, y = (i * 4) & 63;
        float* dst = &Lbw[xx * 65 + y];
        dst[0] = v.x; dst[1] = v.y; dst[2] = v.z; dst[3] = v.w;
    }
    const float* qk = qm + k * 4096 + og * 8 * 64;
    if (t < 128) ((float4*)Lq)[t] = ((const float4*)qk)[t];
    __syncthreads();

    #pragma unroll
    for (int i = 0; i < 4; ++i) {
        int ox = i * 256 + t;               // 1024 outputs: [8 o][128 x]
        int o = ox >> 7, x = ox & 127;
        const float* brow = &Lbw[x * 65];
        const float* qrow = &Lq[o * 64];
        float acc = 0.f;
        #pragma unroll
        for (int y = 0; y < 64; ++y) acc = fmaf(brow[y], qrow[y], acc);
        W2h[(k * 64 + og * 8 + o) * 128 + x] = (_Float16)(acc * 0.0625f);
    }
}

// ---------------- Kernel A2: x fp32 -> fp16 (RNE) into workspace ----------------
__global__ __launch_bounds__(256) void xh_kernel(const float* __restrict__ xg,
                                                 _Float16* __restrict__ xh) {
    const size_t n4 = (size_t)2048 * 128 * 32;      // float4 count
    const size_t stride = (size_t)gridDim.x * 256;
    for (size_t i = (size_t)blockIdx.x * 256 + threadIdx.x; i < n4; i += stride) {
        float4 v = ((const float4*)xg)[i];
        half4_t h;
        h[0] = (_Float16)v.x; h[1] = (_Float16)v.y;
        h[2] = (_Float16)v.z; h[3] = (_Float16)v.w;
        ((half4_t*)xh)[i] = h;
    }
}

// ---------------- Kernel B: fused GEMM + entmax + scale (LDS-free) ----------------
// block = one (b,k); 4 waves; wave w owns o in [16w,16w+16); lane owns o=16w+(l&15)
template<bool PRE>
__global__ __launch_bounds__(256, 6) void satt_kernel(
        const float* __restrict__ xg, const _Float16* __restrict__ Xh,
        const _Float16* __restrict__ W2h,
        const float* __restrict__ values, float* __restrict__ out) {
    // XCD-local remap: bid%8 == b%8, so all 8 k-blocks of one b hit the SAME
    // per-XCD L2 (64 bids apart).
    const int bid = blockIdx.x;
    const int k = (bid & 511) >> 6;
    const int b = ((bid >> 9) << 6) | (bid & 63);
    const int t = threadIdx.x;
    const int w = t >> 6, l = t & 63;
    const int q = l >> 4, c16 = l & 15;
    const int o = w * 16 + c16;             // this lane's output row

    // B-fragments: W2[o][x] rows; b[n=c16][kidx=q*8+j], 4 frags (kk = x/32)
    half8_t bfrag[4];
    const _Float16* w2row = W2h + ((k * 64 + o) << 7);
    #pragma unroll
    for (int kk = 0; kk < 4; ++kk)
        bfrag[kk] = *(const half8_t*)(w2row + kk * 32 + q * 8);

    floatx4 acc[8];
    #pragma unroll
    for (int mt = 0; mt < 8; ++mt) acc[mt] = (floatx4){0.f, 0.f, 0.f, 0.f};

    // A-fragments: x[b][f][x] rows; a[m=c16 -> f=mt*16+c16][kidx=q*8+j]
    if (PRE) {
        const _Float16* xb = Xh + (size_t)b * 16384;
        #pragma unroll
        for (int kk = 0; kk < 4; ++kk) {
            #pragma unroll
            for (int mt = 0; mt < 8; ++mt) {
                half8_t a = *(const half8_t*)(xb + (mt * 16 + c16) * 128 + kk * 32 + q * 8);
                acc[mt] = __builtin_amdgcn_mfma_f32_16x16x32_f16(a, bfrag[kk], acc[mt], 0, 0, 0);
            }
        }
    } else {
        const float* xb = xg + (size_t)b * 16384;
        #pragma unroll
        for (int kk = 0; kk < 4; ++kk) {
            #pragma unroll
            for (int mt = 0; mt < 8; ++mt) {
                const float4* p = (const float4*)(xb + (mt * 16 + c16) * 128 + kk * 32 + q * 8);
                float4 v0 = p[0], v1 = p[1];
                half8_t a;
                a[0] = (_Float16)v0.x; a[1] = (_Float16)v0.y;
                a[2] = (_Float16)v0.z; a[3] = (_Float16)v0.w;
                a[4] = (_Float16)v1.x; a[5] = (_Float16)v1.y;
                a[6] = (_Float16)v1.z; a[7] = (_Float16)v1.w;
                acc[mt] = __builtin_amdgcn_mfma_f32_16x16x32_f16(a, bfrag[kk], acc[mt], 0, 0, 0);
            }
        }
    }

    // ---- Entmax-1.5 on this lane's o-row; lane holds f = mt*16 + q*4 + r ----
    // Partners (same c16, other q) are lanes l^16, l^32.
    float zz[32];
    #pragma unroll
    for (int mt = 0; mt < 8; ++mt) {
        zz[4 * mt + 0] = acc[mt][0]; zz[4 * mt + 1] = acc[mt][1];
        zz[4 * mt + 2] = acc[mt][2]; zz[4 * mt + 3] = acc[mt][3];
    }
    // max, 4 independent chains for ILP
    float m0 = zz[0], m1 = zz[1], m2 = zz[2], m3 = zz[3];
    #pragma unroll
    for (int j = 4; j < 32; j += 4) {
        m0 = fmaxf(m0, zz[j + 0]); m1 = fmaxf(m1, zz[j + 1]);
        m2 = fmaxf(m2, zz[j + 2]); m3 = fmaxf(m3, zz[j + 3]);
    }
    float m = fmaxf(fmaxf(m0, m1), fmaxf(m2, m3));
    m = fmaxf(m, __shfl_xor(m, 16));
    m = fmaxf(m, __shfl_xor(m, 32));

    float tau = m - 1.0f;
    float dm  = 0.9116116523516816f;        // 1 - (1/128)^0.5

#if HAS_FDOT2
    fp16x2 zh[16];
    #pragma unroll
    for (int j = 0; j < 16; ++j)
        zh[j] = __builtin_amdgcn_cvt_pkrtz(zz[2 * j], zz[2 * j + 1]);
    const fp16x2 hzero = { (__fp16)0.f, (__fp16)0.f };
    const fp16x2 hone  = { (__fp16)1.f, (__fp16)1.f };

    #pragma unroll
    for (int it = 0; it < NBIS; ++it) {
        dm *= 0.5f;
        float tm = tau + dm;
        fp16x2 t2 = __builtin_amdgcn_cvt_pkrtz(tm, tm);
        float sa = 0.f, sb = 0.f;
        #pragma unroll
        for (int j = 0; j < 16; j += 2) {
            fp16x2 d0 = __builtin_elementwise_max(zh[j]     - t2, hzero);
            fp16x2 d1 = __builtin_elementwise_max(zh[j + 1] - t2, hzero);
            sa = __builtin_amdgcn_fdot2(d0, d0, sa, false);
            sb = __builtin_amdgcn_fdot2(d1, d1, sb, false);
        }
        float sm = sa + sb;
        sm += __shfl_xor(sm, 16); sm += __shfl_xor(sm, 32);
        tau = (sm >= 1.0f) ? tm : tau;      // f(m-1) >= 0 -> sign test vs 1
    }
    // 2 fp16 Newton steps (monotone for convex f)
    #pragma unroll
    for (int it = 0; it < 2; ++it) {
        fp16x2 t2 = __builtin_amdgcn_cvt_pkrtz(tau, tau);
        float s2a = 0.f, s2b = 0.f, s1a = 0.f, s1b = 0.f;
        #pragma unroll
        for (int j = 0; j < 16; j += 2) {
            fp16x2 d0 = __builtin_elementwise_max(zh[j]     - t2, hzero);
            fp16x2 d1 = __builtin_elementwise_max(zh[j + 1] - t2, hzero);
            s2a = __builtin_amdgcn_fdot2(d0, d0, s2a, false);
            s2b = __builtin_amdgcn_fdot2(d1, d1, s2b, false);
            s1a = __builtin_amdgcn_fdot2(d0, hone, s1a, false);
            s1b = __builtin_amdgcn_fdot2(d1, hone, s1b, false);
        }
        float s2 = s2a + s2b, s1 = s1a + s1b;
        s2 += __shfl_xor(s2, 16); s2 += __shfl_xor(s2, 32);
        s1 += __shfl_xor(s1, 16); s1 += __shfl_xor(s1, 32);
        tau += (s2 - 1.0f) * frcp(fmaxf(s1 + s1, 1e-6f));
    }
#else
    // fallback: fp32 bisection (NBIS+4) + 1 extra fp32 Newton below
    #pragma unroll
    for (int it = 0; it < NBIS + 4; ++it) {
        dm *= 0.5f;
        float tm = tau + dm;
        float sa = 0.f, sb = 0.f;
        #pragma unroll
        for (int j = 0; j < 32; j += 2) {
            float d0 = fmaxf(zz[j] - tm, 0.f);
            float d1 = fmaxf(zz[j + 1] - tm, 0.f);
            sa = fmaf(d0, d0, sa); sb = fmaf(d1, d1, sb);
        }
        float sm = sa + sb;
        sm += __shfl_xor(sm, 16); sm += __shfl_xor(sm, 32);
        tau = (sm >= 1.0f) ? tm : tau;
    }
    {
        float s2a = 0.f, s2b = 0.f, s1a = 0.f, s1b = 0.f;
        #pragma unroll
        for (int j = 0; j < 32; j += 2) {
            float d0 = fmaxf(zz[j] - tau, 0.f);
            float d1 = fmaxf(zz[j + 1] - tau, 0.f);
            s2a = fmaf(d0, d0, s2a); s2b = fmaf(d1, d1, s2b);
            s1a += d0; s1b += d1;
        }
        float s2 = s2a + s2b, s1 = s1a + s1b;
        s2 += __shfl_xor(s2, 16); s2 += __shfl_xor(s2, 32);
        s1 += __shfl_xor(s1, 16); s1 += __shfl_xor(s1, 32);
        tau += (s2 - 1.0f) * frcp(fmaxf(s1 + s1, 1e-6f));
    }
#endif
    // final fp32 Newton polish (removes fp16 root bias; err -> ~1e-5)
    {
        float s2a = 0.f, s2b = 0.f, s1a = 0.f, s1b = 0.f;
        #pragma unroll
        for (int j = 0; j < 32; j += 2) {
            float d0 = fmaxf(zz[j] - tau, 0.f);
            float d1 = fmaxf(zz[j + 1] - tau, 0.f);
            s2a = fmaf(d0, d0, s2a); s2b = fmaf(d1, d1, s2b);
            s1a += d0; s1b += d1;
        }
        float s2 = s2a + s2b, s1 = s1a + s1b;
        s2 += __shfl_xor(s2, 16); s2 += __shfl_xor(s2, 32);
        s1 += __shfl_xor(s1, 16); s1 += __shfl_xor(s1, 32);
        tau += (s2 - 1.0f) * frcp(fmaxf(s1 + s1, 1e-6f));
    }

    // final p, normalization, scale by values
    float ps0 = 0.f, ps1 = 0.f;
    #pragma unroll
    for (int j = 0; j < 32; j += 2) {
        float d0 = fmaxf(zz[j] - tau, 0.f);
        float d1 = fmaxf(zz[j + 1] - tau, 0.f);
        float p0 = d0 * d0, p1 = d1 * d1;
        zz[j] = p0; zz[j + 1] = p1;
        ps0 += p0; ps1 += p1;
    }
    float ps = ps0 + ps1;
    ps += __shfl_xor(ps, 16); ps += __shfl_xor(ps, 32);
    const float inv = 1.0f / ps;

    // lane writes f = mt*16 + q*4 + {0..3} of row o
    const float* vrow = values + ((k * 64 + o) << 7) + q * 4;
    float* orow = out + ((((size_t)b * 8 + k) * 64 + o) << 7) + q * 4;
    #pragma unroll
    for (int mt = 0; mt < 8; ++mt) {
        floatx4 vv = *(const floatx4*)(vrow + mt * 16);
        floatx4 g;
        g[0] = zz[4 * mt + 0] * inv * vv[0];
        g[1] = zz[4 * mt + 1] * inv * vv[1];
        g[2] = zz[4 * mt + 2] * inv * vv[2];
        g[3] = zz[4 * mt + 3] * inv * vv[3];
        *(floatx4*)(orow + mt * 16) = g;
    }
}

extern "C" void kernel_launch(void* const* d_in, const int* in_sizes, int n_in,
                              void* d_out, int out_size, void* d_ws, size_t ws_size,
                              hipStream_t stream) {
    const float* xg     = (const float*)d_in[0];   // [2048,128,128]
    const float* bw     = (const float*)d_in[1];   // [8,128,64]
    const float* qm     = (const float*)d_in[2];   // [8,64,64]
    const float* values = (const float*)d_in[3];   // [8,64,128]
    float* out = (float*)d_out;                    // [2048,8,64,128]
    _Float16* W2h = (_Float16*)d_ws;               // 65536 halves = 128 KB
    _Float16* Xh  = (_Float16*)((char*)d_ws + 131072);  // 64 MB fp16 x

    const size_t need = 131072 + (size_t)2048 * 128 * 128 * 2;

    w2_kernel<<<64, 256, 0, stream>>>(bw, qm, W2h);
    if (ws_size >= need) {
        xh_kernel<<<8192, 256, 0, stream>>>(xg, Xh);
        satt_kernel<true><<<16384, 256, 0, stream>>>(xg, Xh, W2h, values, out);
    } else {
        satt_kernel<false><<<16384, 256, 0, stream>>>(xg, Xh, W2h, values, out);
    }
}

// Round 4
// 889.699 us; speedup vs baseline: 1.0189x; 1.0189x over previous
//
#include <hip/hip_runtime.h>
#include <hip/hip_bf16.h>

// out[b,k,o,f] = entmax15( x[b,f,:] @ W2'[k,:,o] ) * values[k,o,f]
// W2'[k,x,o] = 0.0625 * sum_y bw[k,x,y] * q[k,o,y]   (scale * (alpha-1) folded in)
// b=2048, k=8, o=64, f=128, x=128, y=64
//
// Structure: NO LDS, NO barriers in the hot kernel. MFMA computes z^T:
// A = x[b] ([f][x] rows), B = W2 ([o][x] rows), both as half8 fragments from
// global (L2/L3-resident, XCD-local bid remap). Each lane's 32 acc values are
// 32 f's of ONE o-row; entmax reduces via shfl_xor 16/32.
// Round-4: launch_bounds(256,4) (VGPR cap 128) + manual 2-bank A-frag
// double-buffer so 8 loads stay in flight across the kk chain (round-3 was
// serialized at VGPR=40 -> pure L2-latency-bound, MfmaUtil 3.5%).

using half8_t  = __attribute__((ext_vector_type(8))) _Float16;
using half4_t  = __attribute__((ext_vector_type(4))) _Float16;
using fp16x2   = __attribute__((ext_vector_type(2))) __fp16;   // builtin-compatible
using floatx4  = __attribute__((ext_vector_type(4))) float;

#define NBIS 8    // fp16 bisection iters -> bracket width 0.91*2^-8*2 = 7.1e-3

#if defined(__has_builtin)
#if __has_builtin(__builtin_amdgcn_fdot2)
#define HAS_FDOT2 1
#endif
#endif
#ifndef HAS_FDOT2
#define HAS_FDOT2 0
#endif

__device__ __forceinline__ float frcp(float x) {
#if __has_builtin(__builtin_amdgcn_rcpf)
    return __builtin_amdgcn_rcpf(x);   // 1-ulp rcp; plenty for Newton step sizing
#else
    return 1.0f / x;
#endif
}

// ---------------- Kernel A: W2'[k][o][x] fp16 into workspace ----------------
__global__ __launch_bounds__(256) void w2_kernel(const float* __restrict__ bw,
                                                 const float* __restrict__ qm,
                                                 _Float16* __restrict__ W2h) {
    const int k  = blockIdx.x >> 3;
    const int og = blockIdx.x & 7;          // o-chunk of 8 rows
    __shared__ float Lbw[128 * 65];         // [x][y] padded (+1) -> conflict-free
    __shared__ float Lq[8 * 64];            // [o][y]
    const int t = threadIdx.x;

    const float* bwk = bw + k * 8192;       // [128][64]
    #pragma unroll
    for (int i2 = 0; i2 < 8; ++i2) {
        int i = t + i2 * 256;               // float4 index, 2048 total
        float4 v = ((const float4*)bwk)[i];
        int xx = (i * 4) >> 6, y = (i * 4) & 63;
        float* dst = &Lbw[xx * 65 + y];
        dst[0] = v.x; dst[1] = v.y; dst[2] = v.z; dst[3] = v.w;
    }
    const float* qk = qm + k * 4096 + og * 8 * 64;
    if (t < 128) ((float4*)Lq)[t] = ((const float4*)qk)[t];
    __syncthreads();

    #pragma unroll
    for (int i = 0; i < 4; ++i) {
        int ox = i * 256 + t;               // 1024 outputs: [8 o][128 x]
        int o = ox >> 7, x = ox & 127;
        const float* brow = &Lbw[x * 65];
        const float* qrow = &Lq[o * 64];
        float acc = 0.f;
        #pragma unroll
        for (int y = 0; y < 64; ++y) acc = fmaf(brow[y], qrow[y], acc);
        W2h[(k * 64 + og * 8 + o) * 128 + x] = (_Float16)(acc * 0.0625f);
    }
}

// ---------------- Kernel A2: x fp32 -> fp16 (RNE) into workspace ----------------
__global__ __launch_bounds__(256) void xh_kernel(const float* __restrict__ xg,
                                                 _Float16* __restrict__ xh) {
    const size_t n4 = (size_t)2048 * 128 * 32;      // float4 count
    const size_t stride = (size_t)gridDim.x * 256;
    for (size_t i = (size_t)blockIdx.x * 256 + threadIdx.x; i < n4; i += stride) {
        float4 v = ((const float4*)xg)[i];
        half4_t h;
        h[0] = (_Float16)v.x; h[1] = (_Float16)v.y;
        h[2] = (_Float16)v.z; h[3] = (_Float16)v.w;
        ((half4_t*)xh)[i] = h;
    }
}

// ---------------- Kernel B: fused GEMM + entmax + scale (LDS-free) ----------------
// block = one (b,k); 4 waves; wave w owns o in [16w,16w+16); lane owns o=16w+(l&15)
template<bool PRE>
__global__ __launch_bounds__(256, 4) void satt_kernel(
        const float* __restrict__ xg, const _Float16* __restrict__ Xh,
        const _Float16* __restrict__ W2h,
        const float* __restrict__ values, float* __restrict__ out) {
    // XCD-local remap: bid%8 == b%8, so all 8 k-blocks of one b hit the SAME
    // per-XCD L2 (64 bids apart).
    const int bid = blockIdx.x;
    const int k = (bid & 511) >> 6;
    const int b = ((bid >> 9) << 6) | (bid & 63);
    const int t = threadIdx.x;
    const int w = t >> 6, l = t & 63;
    const int q = l >> 4, c16 = l & 15;
    const int o = w * 16 + c16;             // this lane's output row

    // B-fragments: W2[o][x] rows; b[n=c16][kidx=q*8+j], 4 frags (kk = x/32)
    half8_t bfrag[4];
    const _Float16* w2row = W2h + ((k * 64 + o) << 7);
    #pragma unroll
    for (int kk = 0; kk < 4; ++kk)
        bfrag[kk] = *(const half8_t*)(w2row + kk * 32 + q * 8);

    floatx4 acc[8];
    #pragma unroll
    for (int mt = 0; mt < 8; ++mt) acc[mt] = (floatx4){0.f, 0.f, 0.f, 0.f};

    // A-fragments: x[b][f][x] rows; a[m=c16 -> f=mt*16+c16][kidx=q*8+j]
    // Manual 2-bank double-buffer: 8 loads in flight while 8 MFMAs run.
    if (PRE) {
        const _Float16* xb = Xh + (size_t)b * 16384 + c16 * 128 + q * 8;
        half8_t aA[8], aB[8];
        #pragma unroll
        for (int mt = 0; mt < 8; ++mt)
            aA[mt] = *(const half8_t*)(xb + mt * 2048 + 0 * 32);
        #pragma unroll
        for (int mt = 0; mt < 8; ++mt)
            aB[mt] = *(const half8_t*)(xb + mt * 2048 + 1 * 32);
        #pragma unroll
        for (int mt = 0; mt < 8; ++mt)
            acc[mt] = __builtin_amdgcn_mfma_f32_16x16x32_f16(aA[mt], bfrag[0], acc[mt], 0, 0, 0);
        #pragma unroll
        for (int mt = 0; mt < 8; ++mt)
            aA[mt] = *(const half8_t*)(xb + mt * 2048 + 2 * 32);
        #pragma unroll
        for (int mt = 0; mt < 8; ++mt)
            acc[mt] = __builtin_amdgcn_mfma_f32_16x16x32_f16(aB[mt], bfrag[1], acc[mt], 0, 0, 0);
        #pragma unroll
        for (int mt = 0; mt < 8; ++mt)
            aB[mt] = *(const half8_t*)(xb + mt * 2048 + 3 * 32);
        #pragma unroll
        for (int mt = 0; mt < 8; ++mt)
            acc[mt] = __builtin_amdgcn_mfma_f32_16x16x32_f16(aA[mt], bfrag[2], acc[mt], 0, 0, 0);
        #pragma unroll
        for (int mt = 0; mt < 8; ++mt)
            acc[mt] = __builtin_amdgcn_mfma_f32_16x16x32_f16(aB[mt], bfrag[3], acc[mt], 0, 0, 0);
    } else {
        const float* xb = xg + (size_t)b * 16384;
        #pragma unroll
        for (int kk = 0; kk < 4; ++kk) {
            #pragma unroll
            for (int mt = 0; mt < 8; ++mt) {
                const float4* p = (const float4*)(xb + (mt * 16 + c16) * 128 + kk * 32 + q * 8);
                float4 v0 = p[0], v1 = p[1];
                half8_t a;
                a[0] = (_Float16)v0.x; a[1] = (_Float16)v0.y;
                a[2] = (_Float16)v0.z; a[3] = (_Float16)v0.w;
                a[4] = (_Float16)v1.x; a[5] = (_Float16)v1.y;
                a[6] = (_Float16)v1.z; a[7] = (_Float16)v1.w;
                acc[mt] = __builtin_amdgcn_mfma_f32_16x16x32_f16(a, bfrag[kk], acc[mt], 0, 0, 0);
            }
        }
    }

    // ---- Entmax-1.5 on this lane's o-row; lane holds f = mt*16 + q*4 + r ----
    // Partners (same c16, other q) are lanes l^16, l^32.
    float zz[32];
    #pragma unroll
    for (int mt = 0; mt < 8; ++mt) {
        zz[4 * mt + 0] = acc[mt][0]; zz[4 * mt + 1] = acc[mt][1];
        zz[4 * mt + 2] = acc[mt][2]; zz[4 * mt + 3] = acc[mt][3];
    }
    // max, 4 independent chains for ILP
    float m0 = zz[0], m1 = zz[1], m2 = zz[2], m3 = zz[3];
    #pragma unroll
    for (int j = 4; j < 32; j += 4) {
        m0 = fmaxf(m0, zz[j + 0]); m1 = fmaxf(m1, zz[j + 1]);
        m2 = fmaxf(m2, zz[j + 2]); m3 = fmaxf(m3, zz[j + 3]);
    }
    float m = fmaxf(fmaxf(m0, m1), fmaxf(m2, m3));
    m = fmaxf(m, __shfl_xor(m, 16));
    m = fmaxf(m, __shfl_xor(m, 32));

    float tau = m - 1.0f;
    float dm  = 0.9116116523516816f;        // 1 - (1/128)^0.5

#if HAS_FDOT2
    fp16x2 zh[16];
    #pragma unroll
    for (int j = 0; j < 16; ++j)
        zh[j] = __builtin_amdgcn_cvt_pkrtz(zz[2 * j], zz[2 * j + 1]);
    const fp16x2 hzero = { (__fp16)0.f, (__fp16)0.f };
    const fp16x2 hone  = { (__fp16)1.f, (__fp16)1.f };

    #pragma unroll
    for (int it = 0; it < NBIS; ++it) {
        dm *= 0.5f;
        float tm = tau + dm;
        fp16x2 t2 = __builtin_amdgcn_cvt_pkrtz(tm, tm);
        float sa = 0.f, sb = 0.f;
        #pragma unroll
        for (int j = 0; j < 16; j += 2) {
            fp16x2 d0 = __builtin_elementwise_max(zh[j]     - t2, hzero);
            fp16x2 d1 = __builtin_elementwise_max(zh[j + 1] - t2, hzero);
            sa = __builtin_amdgcn_fdot2(d0, d0, sa, false);
            sb = __builtin_amdgcn_fdot2(d1, d1, sb, false);
        }
        float sm = sa + sb;
        sm += __shfl_xor(sm, 16); sm += __shfl_xor(sm, 32);
        tau = (sm >= 1.0f) ? tm : tau;      // f(m-1) >= 0 -> sign test vs 1
    }
    // 2 fp16 Newton steps (monotone for convex f)
    #pragma unroll
    for (int it = 0; it < 2; ++it) {
        fp16x2 t2 = __builtin_amdgcn_cvt_pkrtz(tau, tau);
        float s2a = 0.f, s2b = 0.f, s1a = 0.f, s1b = 0.f;
        #pragma unroll
        for (int j = 0; j < 16; j += 2) {
            fp16x2 d0 = __builtin_elementwise_max(zh[j]     - t2, hzero);
            fp16x2 d1 = __builtin_elementwise_max(zh[j + 1] - t2, hzero);
            s2a = __builtin_amdgcn_fdot2(d0, d0, s2a, false);
            s2b = __builtin_amdgcn_fdot2(d1, d1, s2b, false);
            s1a = __builtin_amdgcn_fdot2(d0, hone, s1a, false);
            s1b = __builtin_amdgcn_fdot2(d1, hone, s1b, false);
        }
        float s2 = s2a + s2b, s1 = s1a + s1b;
        s2 += __shfl_xor(s2, 16); s2 += __shfl_xor(s2, 32);
        s1 += __shfl_xor(s1, 16); s1 += __shfl_xor(s1, 32);
        tau += (s2 - 1.0f) * frcp(fmaxf(s1 + s1, 1e-6f));
    }
#else
    // fallback: fp32 bisection (NBIS+4) + 1 extra fp32 Newton below
    #pragma unroll
    for (int it = 0; it < NBIS + 4; ++it) {
        dm *= 0.5f;
        float tm = tau + dm;
        float sa = 0.f, sb = 0.f;
        #pragma unroll
        for (int j = 0; j < 32; j += 2) {
            float d0 = fmaxf(zz[j] - tm, 0.f);
            float d1 = fmaxf(zz[j + 1] - tm, 0.f);
            sa = fmaf(d0, d0, sa); sb = fmaf(d1, d1, sb);
        }
        float sm = sa + sb;
        sm += __shfl_xor(sm, 16); sm += __shfl_xor(sm, 32);
        tau = (sm >= 1.0f) ? tm : tau;
    }
    {
        float s2a = 0.f, s2b = 0.f, s1a = 0.f, s1b = 0.f;
        #pragma unroll
        for (int j = 0; j < 32; j += 2) {
            float d0 = fmaxf(zz[j] - tau, 0.f);
            float d1 = fmaxf(zz[j + 1] - tau, 0.f);
            s2a = fmaf(d0, d0, s2a); s2b = fmaf(d1, d1, s2b);
            s1a += d0; s1b += d1;
        }
        float s2 = s2a + s2b, s1 = s1a + s1b;
        s2 += __shfl_xor(s2, 16); s2 += __shfl_xor(s2, 32);
        s1 += __shfl_xor(s1, 16); s1 += __shfl_xor(s1, 32);
        tau += (s2 - 1.0f) * frcp(fmaxf(s1 + s1, 1e-6f));
    }
#endif
    // final fp32 Newton polish (removes fp16 root bias; err -> ~1e-5)
    {
        float s2a = 0.f, s2b = 0.f, s1a = 0.f, s1b = 0.f;
        #pragma unroll
        for (int j = 0; j < 32; j += 2) {
            float d0 = fmaxf(zz[j] - tau, 0.f);
            float d1 = fmaxf(zz[j + 1] - tau, 0.f);
            s2a = fmaf(d0, d0, s2a); s2b = fmaf(d1, d1, s2b);
            s1a += d0; s1b += d1;
        }
        float s2 = s2a + s2b, s1 = s1a + s1b;
        s2 += __shfl_xor(s2, 16); s2 += __shfl_xor(s2, 32);
        s1 += __shfl_xor(s1, 16); s1 += __shfl_xor(s1, 32);
        tau += (s2 - 1.0f) * frcp(fmaxf(s1 + s1, 1e-6f));
    }

    // final p, normalization, scale by values
    float ps0 = 0.f, ps1 = 0.f;
    #pragma unroll
    for (int j = 0; j < 32; j += 2) {
        float d0 = fmaxf(zz[j] - tau, 0.f);
        float d1 = fmaxf(zz[j + 1] - tau, 0.f);
        float p0 = d0 * d0, p1 = d1 * d1;
        zz[j] = p0; zz[j + 1] = p1;
        ps0 += p0; ps1 += p1;
    }
    float ps = ps0 + ps1;
    ps += __shfl_xor(ps, 16); ps += __shfl_xor(ps, 32);
    const float inv = 1.0f / ps;

    // lane writes f = mt*16 + q*4 + {0..3} of row o
    const float* vrow = values + ((k * 64 + o) << 7) + q * 4;
    float* orow = out + ((((size_t)b * 8 + k) * 64 + o) << 7) + q * 4;
    #pragma unroll
    for (int mt = 0; mt < 8; ++mt) {
        floatx4 vv = *(const floatx4*)(vrow + mt * 16);
        floatx4 g;
        g[0] = zz[4 * mt + 0] * inv * vv[0];
        g[1] = zz[4 * mt + 1] * inv * vv[1];
        g[2] = zz[4 * mt + 2] * inv * vv[2];
        g[3] = zz[4 * mt + 3] * inv * vv[3];
        *(floatx4*)(orow + mt * 16) = g;
    }
}

extern "C" void kernel_launch(void* const* d_in, const int* in_sizes, int n_in,
                              void* d_out, int out_size, void* d_ws, size_t ws_size,
                              hipStream_t stream) {
    const float* xg     = (const float*)d_in[0];   // [2048,128,128]
    const float* bw     = (const float*)d_in[1];   // [8,128,64]
    const float* qm     = (const float*)d_in[2];   // [8,64,64]
    const float* values = (const float*)d_in[3];   // [8,64,128]
    float* out = (float*)d_out;                    // [2048,8,64,128]
    _Float16* W2h = (_Float16*)d_ws;               // 65536 halves = 128 KB
    _Float16* Xh  = (_Float16*)((char*)d_ws + 131072);  // 64 MB fp16 x

    const size_t need = 131072 + (size_t)2048 * 128 * 128 * 2;

    w2_kernel<<<64, 256, 0, stream>>>(bw, qm, W2h);
    if (ws_size >= need) {
        xh_kernel<<<8192, 256, 0, stream>>>(xg, Xh);
        satt_kernel<true><<<16384, 256, 0, stream>>>(xg, Xh, W2h, values, out);
    } else {
        satt_kernel<false><<<16384, 256, 0, stream>>>(xg, Xh, W2h, values, out);
    }
}